// Round 10
// baseline (319.620 us; speedup 1.0000x reference)
//
#include <hip/hip_runtime.h>
#include <hip/hip_fp16.h>
#include <cstdint>
#include <cstddef>

#define F_IN 128
#define HID 16
#define NBUK 1024          // bucket = node >> 7
#define NPB  128           // nodes per bucket
#define CHUNK 8192         // edges per histogram block
#define CHUNK2 16384       // edges per scatter block (16-edge runs = 64B lines)

typedef float f4v __attribute__((ext_vector_type(4)));
typedef float f2v __attribute__((ext_vector_type(2)));
typedef int   i2v __attribute__((ext_vector_type(2)));
typedef int   i4v __attribute__((ext_vector_type(4)));
typedef _Float16 h8 __attribute__((ext_vector_type(8)));

// ---------------- index-width detection ----------------
// int64 little-endian with values < 2^31 => every odd 32-bit word of the
// first 64 entries is zero. Flag: 1 = int64, 0 = int32.
__global__ void k_detect(const int* __restrict__ eidx, int* __restrict__ flag) {
    if (blockIdx.x == 0 && threadIdx.x == 0) {
        int all0 = 1;
        for (int i = 0; i < 64; ++i) {
            if (eidx[2 * i + 1] != 0) { all0 = 0; break; }
        }
        *flag = all0;
    }
}

__device__ __forceinline__ int ld_idx_nt(const int* __restrict__ p, int e, int is64) {
    return is64 ? __builtin_nontemporal_load(&p[2 * e])
                : __builtin_nontemporal_load(&p[e]);
}

// ---------------- bucket histogram (LDS-staged, int atomics) ----------------
__launch_bounds__(256)
__global__ void k_bhist(const int* __restrict__ eidx, int E,
                        const int* __restrict__ flag, int* __restrict__ ghist) {
    __shared__ int lh[NBUK];
    int t = threadIdx.x;
    for (int i = t; i < NBUK; i += 256) lh[i] = 0;
    __syncthreads();
    int base = blockIdx.x * CHUNK;
    int cnt = min(CHUNK, E - base);
    int is64 = *flag;
    const int* colp = eidx + ((size_t)E << is64);
    for (int i = t; i < cnt; i += 256)
        atomicAdd(&lh[ld_idx_nt(colp, base + i, is64) >> 7], 1);
    __syncthreads();
    for (int i = t; i < NBUK; i += 256)
        if (lh[i]) atomicAdd(&ghist[i], lh[i]);
}

// ---------------- exact scan of 1024 bucket counts (single block) ----------------
__global__ void k_bscan(const int* __restrict__ ghist, int E,
                        int* __restrict__ boff, int* __restrict__ gcur) {
    __shared__ int s[NBUK];
    int t = threadIdx.x;
    int v = ghist[t];
    s[t] = v;
    __syncthreads();
    for (int off = 1; off < NBUK; off <<= 1) {
        int a = (t >= off) ? s[t - off] : 0;
        __syncthreads();
        s[t] += a;
        __syncthreads();
    }
    int excl = s[t] - v;
    boff[t] = excl;
    gcur[t] = excl;
    if (t == NBUK - 1) boff[NBUK] = E;
}

// ------- bucket scatter: LDS cursor per bucket; 16-edge runs = full L2 lines -------
// pairs[k] = r | (c&127)<<20, grouped by bucket (c>>7)
__launch_bounds__(512)
__global__ void k_bscatter(const int* __restrict__ eidx, int E,
                           const int* __restrict__ flag,
                           int* __restrict__ gcur, uint32_t* __restrict__ pairs) {
    __shared__ int lh[NBUK];
    __shared__ int lcur[NBUK];
    int t = threadIdx.x;
    for (int i = t; i < NBUK; i += 512) lh[i] = 0;
    __syncthreads();
    int base = blockIdx.x * CHUNK2;
    int cnt = min(CHUNK2, E - base);
    int is64 = *flag;
    const int* rowp = eidx;
    const int* colp = eidx + ((size_t)E << is64);
    for (int i = t; i < cnt; i += 512)
        atomicAdd(&lh[ld_idx_nt(colp, base + i, is64) >> 7], 1);
    __syncthreads();
    for (int i = t; i < NBUK; i += 512) {
        int c = lh[i];
        lcur[i] = c ? atomicAdd(&gcur[i], c) : 0;   // reserve contiguous run
    }
    __syncthreads();
    for (int i = t; i < cnt; i += 512) {
        int e = base + i;
        int c = ld_idx_nt(colp, e, is64);
        int r = ld_idx_nt(rowp, e, is64);
        int buk = c >> 7;
        int pos = atomicAdd(&lcur[buk], 1);
        pairs[pos] = (uint32_t)r | ((uint32_t)(c & (NPB - 1)) << 20);
    }
}

// ------- per-bucket counting sort -> per-node CSR (srcs, noff) + dinv -------
__launch_bounds__(256)
__global__ void k_bsort(const uint32_t* __restrict__ pairs, const int* __restrict__ boff,
                        int* __restrict__ srcs, int* __restrict__ noff,
                        float* __restrict__ dinv, int n) {
    __shared__ int cnt[NPB];
    __shared__ int scn[NPB];
    int t = threadIdx.x;
    int b = blockIdx.x;
    if (t < NPB) cnt[t] = 0;
    __syncthreads();
    int beg = boff[b], end = boff[b + 1];
    for (int k = beg + t; k < end; k += 256)
        atomicAdd(&cnt[pairs[k] >> 20], 1);
    __syncthreads();
    if (t < NPB) scn[t] = cnt[t];
    __syncthreads();
    for (int off = 1; off < NPB; off <<= 1) {
        int v = 0;
        if (t < NPB && t >= off) v = scn[t - off];
        __syncthreads();
        if (t < NPB) scn[t] += v;
        __syncthreads();
    }
    if (t < NPB) {
        int node = b * NPB + t;
        int excl = scn[t] - cnt[t];
        if (node <= n) noff[node] = beg + excl;      // node==n lands here (last bucket)
        if (node < n)  dinv[node] = rsqrtf((float)cnt[t] + 1.0f);
        cnt[t] = beg + excl;                         // reuse as cursor
    }
    __syncthreads();
    for (int k = beg + t; k < end; k += 256) {
        uint32_t p = pairs[k];
        int pos = atomicAdd(&cnt[p >> 20], 1);
        srcs[pos] = (int)(p & 0xFFFFF);
    }
}

// ------- hs1 = (x @ W1) * dinv[row], fp16 ----------------
__launch_bounds__(256)
__global__ void k_gemm1(const float* __restrict__ x, const float* __restrict__ W1,
                        const float* __restrict__ dinv, __half* __restrict__ hs, int n) {
    __shared__ float Wt[16 * 132];
    for (int i = threadIdx.x; i < F_IN * HID; i += 256) {
        int k = i >> 4, j = i & 15;
        Wt[j * 132 + k] = W1[i];
    }
    __syncthreads();
    int row = blockIdx.x * 16 + (threadIdx.x >> 4);
    int j = threadIdx.x & 15;
    if (row >= n) return;
    const f4v* xr = (const f4v*)(x + (size_t)row * F_IN);
    float acc = 0.f;
#pragma unroll
    for (int kk = 0; kk < 32; ++kk) {
        f4v xv = __builtin_nontemporal_load(&xr[kk]);   // stream: don't pollute L2
        float4 wv = *(const float4*)&Wt[j * 132 + 4 * kk];
        acc += xv.x * wv.x + xv.y * wv.y + xv.z * wv.z + xv.w * wv.w;
    }
    hs[(size_t)row * HID + j] = __float2half(acc * dinv[row]);
}

// ------- fused GCN layer: CSR gather, register accumulate -------
// Each 16-lane group owns one node i; lane j owns feature j.
// acc = hs[i][j] + sum_{r in N(i)} hs[r][j]        (hs pre-scaled by dinv[src])
// hrelu[j] = relu(acc * dinv[i] + bias[j])
// EPI 0: out0 = fp16( (hrelu @ Wnext) * dinv )     (next layer's hs)
// EPI 1: out0 = fp16( hrelu )                      (h2 for the edge-MLP MFMA)
// NOTE: n % 16 == 0 (100000): no partial groups, uniform barriers.
template <int EPI>
__launch_bounds__(256)
__global__ void k_layer(const int* __restrict__ srcs, const int* __restrict__ noff,
                        const __half* __restrict__ hs, const float* __restrict__ dinv,
                        const float* __restrict__ bias, const float* __restrict__ Wnext,
                        __half* __restrict__ out0) {
    __shared__ float Ws[256];
    __shared__ float bs[16];
    __shared__ float srow[16 * 17];
    int t = threadIdx.x;
    if (EPI == 0) { if (t < 256) Ws[t] = Wnext[t]; }
    if (t < 16) bs[t] = bias[t];
    __syncthreads();

    int i = blockIdx.x * 16 + (t >> 4);    // node
    int j = t & 15;                        // feature
    int beg = noff[i], end = noff[i + 1];
    float acc = __half2float(hs[(size_t)i * HID + j]);   // self-loop term

    int kb = beg;
    for (; kb + 16 <= end; kb += 16) {
        int idx = __builtin_nontemporal_load(&srcs[kb + j]);   // coalesced stream
#pragma unroll
        for (int m = 0; m < 16; ++m) {
            int r = __shfl(idx, m, 16);    // broadcast within the 16-lane group
            acc += __half2float(hs[(size_t)r * HID + j]);
        }
    }
    if (kb < end) {
        int lim = end - kb;
        int idx = srcs[kb + ((j < lim) ? j : (lim - 1))];
        for (int m = 0; m < lim; ++m) {
            int r = __shfl(idx, m, 16);
            acc += __half2float(hs[(size_t)r * HID + j]);
        }
    }

    float di = dinv[i];
    float hrelu = fmaxf(acc * di + bs[j], 0.f);
    if (EPI == 1) {
        out0[(size_t)i * HID + j] = __float2half(hrelu);
        return;
    }
    int ln = t >> 4;
    srow[ln * 17 + j] = hrelu;
    __syncthreads();
    float a0 = 0.f;
#pragma unroll
    for (int k = 0; k < 16; ++k) a0 += srow[ln * 17 + k] * Ws[k * 16 + j];
    out0[(size_t)i * HID + j] = __float2half(a0 * di);
}

// ------- edge MLP via MFMA: z[16 edges][16] = [h2[r]|h2[c]] @ [A;B] + b1 -------
// One mfma_f32_16x16x32_f16 per 16 edges. h2 = 3.2 MB, fits per-XCD L2.
// A-frag: lane l -> row=l&15 (edge), k=8*(l>>4)+j  (kblock 0,1 -> h2[r]; 2,3 -> h2[c])
// B-frag: lane l -> B[8*(l>>4)+j][l&15]  (weights, persistent in 4 VGPRs)
// C/D:    lane l -> col=l&15 (z-dim), row=(l>>4)*4+reg (edge)   [m89 verified]
#define EDGE_ITER 8
__launch_bounds__(256)
__global__ void k_edge(const int* __restrict__ eidx, int E,
                       const int* __restrict__ flag,
                       const _Float16* __restrict__ h2,
                       const float* __restrict__ fc1W, const float* __restrict__ fc1b,
                       const float* __restrict__ fc2W, const float* __restrict__ fc2b,
                       float* __restrict__ out) {
    int t = threadIdx.x;
    int l = t & 63;
    int wv = t >> 6;                       // wave 0..3
    int m = l & 15;
    int kb = l >> 4;                       // 0..3
    int side = kb >> 1;                    // 0 -> r, 1 -> c
    int part = kb & 1;                     // which 8-feature half

    // persistent B fragment: W[32][16] = [fc1W rows 0..31]
    h8 bf;
#pragma unroll
    for (int j = 0; j < 8; ++j)
        bf[j] = (_Float16)fc1W[(8 * kb + j) * 16 + m];
    float b1v = fc1b[m];
    f4v cinit; cinit.x = b1v; cinit.y = b1v; cinit.z = b1v; cinit.w = b1v;
    float w20 = fc2W[2 * m], w21 = fc2W[2 * m + 1];
    float b20 = fc2b[0], b21 = fc2b[1];

    int is64 = *flag;
    const int* rowp = eidx;
    const int* colp = eidx + ((size_t)E << is64);
    const int* idxp = side ? colp : rowp;

    for (int it = 0; it < EDGE_ITER; ++it) {
        int grp = (blockIdx.x * EDGE_ITER + it) * 4 + wv;
        int base = grp * 16;
        if (base >= E) return;
        int eA = base + m;
        if (eA >= E) eA = E - 1;
        int node = ld_idx_nt(idxp, eA, is64);
        h8 av = *(const h8*)(h2 + (size_t)node * HID + part * 8);
        f4v z = __builtin_amdgcn_mfma_f32_16x16x32_f16(av, bf, cinit, 0, 0, 0);
        // epilogue: relu, x fc2W, reduce over col (lane&15), log-softmax
        float l0[4], l1[4];
#pragma unroll
        for (int q = 0; q < 4; ++q) {
            float zr = fmaxf(z[q], 0.f);
            float v0 = zr * w20, v1 = zr * w21;
#pragma unroll
            for (int msk = 1; msk < 16; msk <<= 1) {
                v0 += __shfl_xor(v0, msk);
                v1 += __shfl_xor(v1, msk);
            }
            float a = b20 + v0, b = b21 + v1;
            float mm = fmaxf(a, b);
            float lse = mm + __logf(__expf(a - mm) + __expf(b - mm));
            l0[q] = a - lse; l1[q] = b - lse;
        }
        if (m == 0) {
            int e0 = base + kb * 4;        // rows kb*4 .. kb*4+3
            if (e0 + 3 < E) {
                f4v o1; o1.x = l0[0]; o1.y = l1[0]; o1.z = l0[1]; o1.w = l1[1];
                f4v o2; o2.x = l0[2]; o2.y = l1[2]; o2.z = l0[3]; o2.w = l1[3];
                __builtin_nontemporal_store(o1, (f4v*)(out + 2 * (size_t)e0));
                __builtin_nontemporal_store(o2, (f4v*)(out + 2 * (size_t)e0 + 4));
            } else {
                for (int q = 0; q < 4; ++q) {
                    if (e0 + q < E) {
                        f2v o; o.x = l0[q]; o.y = l1[q];
                        __builtin_nontemporal_store(o, (f2v*)(out + 2 * (size_t)(e0 + q)));
                    }
                }
            }
        }
    }
}

static inline size_t rnd4(size_t v) { return (v + 3) & ~(size_t)3; }

extern "C" void kernel_launch(void* const* d_in, const int* in_sizes, int n_in,
                              void* d_out, int out_size, void* d_ws, size_t ws_size,
                              hipStream_t stream) {
    const float* x    = (const float*)d_in[0];
    const int*   eidx = (const int*)d_in[1];
    const float* W1   = (const float*)d_in[2];
    const float* b1   = (const float*)d_in[3];
    const float* W2   = (const float*)d_in[4];
    const float* b2   = (const float*)d_in[5];
    const float* fc1W = (const float*)d_in[6];
    const float* fc1b = (const float*)d_in[7];
    const float* fc2W = (const float*)d_in[8];
    const float* fc2b = (const float*)d_in[9];

    const int n = in_sizes[0] / F_IN;   // 100000 (divisible by 16)
    const int E = in_sizes[1] / 2;      // 3200000
    const int NBLK_HIST = (E + CHUNK - 1) / CHUNK;     // 391
    const int NBLK_SCAT = (E + CHUNK2 - 1) / CHUNK2;   // 196
    const int NBLK_BUK  = (n + NPB - 1) / NPB;         // 782

    // workspace carve-up (float units, 16B-aligned regions)
    float* ws = (float*)d_ws;
    size_t a = 0;
    float*    dinv  = ws + a;              a += rnd4(n);
    uint32_t* pairs = (uint32_t*)(ws + a); a += rnd4(E);
    int*      srcs  = (int*)(ws + a);      a += rnd4(E);
    int*      noff  = (int*)(ws + a);      a += rnd4(n + 1);
    int*      boff  = (int*)(ws + a);      a += rnd4(NBUK + 1);
    int*      gcur  = (int*)(ws + a);      a += NBUK;
    int*      ghist = (int*)(ws + a);      a += NBUK;
    int*      flag  = (int*)(ws + a);      a += 4;
    __half*   hs1   = (__half*)(ws + a);   a += rnd4((size_t)n * HID / 2);
    __half*   hs2   = (__half*)(ws + a);   a += rnd4((size_t)n * HID / 2);
    __half*   h2b   = (__half*)(ws + a);   a += rnd4((size_t)n * HID / 2);
    float* out = (float*)d_out;

    k_detect<<<1, 64, 0, stream>>>(eidx, flag);

    // ---- two-level bucket sort -> per-node CSR (shared by both layers) ----
    (void)hipMemsetAsync(ghist, 0, NBUK * sizeof(int), stream);
    k_bhist<<<NBLK_HIST, 256, 0, stream>>>(eidx, E, flag, ghist);
    k_bscan<<<1, NBUK, 0, stream>>>(ghist, E, boff, gcur);
    k_bscatter<<<NBLK_SCAT, 512, 0, stream>>>(eidx, E, flag, gcur, pairs);
    k_bsort<<<NBLK_BUK, 256, 0, stream>>>(pairs, boff, srcs, noff, dinv, n);

    // ---- dense prologue: hs1 = (x@W1)*dinv (fp16) ----
    k_gemm1<<<(n + 15) / 16, 256, 0, stream>>>(x, W1, dinv, hs1, n);

    // ---- layer 1 (epilogue: hs2 = relu(gcn)@W2 * dinv, fp16) ----
    k_layer<0><<<n / 16, 256, 0, stream>>>(srcs, noff, hs1, dinv, b1, W2, hs2);
    // ---- layer 2 (plain relu output h2, fp16: 3.2 MB, fits per-XCD L2) ----
    k_layer<1><<<n / 16, 256, 0, stream>>>(srcs, noff, hs2, dinv, b2, nullptr, h2b);
    // ---- edge MLP + log_softmax via MFMA (16 edges per mfma) ----
    {
        int ngrp = (E + 15) / 16;                       // 200000
        int nblk = (ngrp + 4 * EDGE_ITER - 1) / (4 * EDGE_ITER);   // 6250
        k_edge<<<nblk, 256, 0, stream>>>(eidx, E, flag, (const _Float16*)h2b,
                                         fc1W, fc1b, fc2W, fc2b, out);
    }
}

// Round 11
// 288.063 us; speedup vs baseline: 1.1095x; 1.1095x over previous
//
#include <hip/hip_runtime.h>
#include <hip/hip_fp16.h>
#include <cstdint>
#include <cstddef>

#define F_IN 128
#define HID 16
#define NBUK 1024          // bucket = node >> 7
#define NPB  128           // nodes per bucket
#define CHUNK2 16384       // edges per hist/scatter block (16-edge runs = 64B lines)

typedef float f4v __attribute__((ext_vector_type(4)));
typedef float f2v __attribute__((ext_vector_type(2)));
typedef int   i2v __attribute__((ext_vector_type(2)));
typedef int   i4v __attribute__((ext_vector_type(4)));
typedef _Float16 h8 __attribute__((ext_vector_type(8)));

// ---------------- index-width detection ----------------
// int64 little-endian with values < 2^31 => every odd 32-bit word of the
// first 64 entries is zero. Flag: 1 = int64, 0 = int32.
__global__ void k_detect(const int* __restrict__ eidx, int* __restrict__ flag) {
    if (blockIdx.x == 0 && threadIdx.x == 0) {
        int all0 = 1;
        for (int i = 0; i < 64; ++i) {
            if (eidx[2 * i + 1] != 0) { all0 = 0; break; }
        }
        *flag = all0;
    }
}

__device__ __forceinline__ int ld_idx_nt(const int* __restrict__ p, int e, int is64) {
    return is64 ? __builtin_nontemporal_load(&p[2 * e])
                : __builtin_nontemporal_load(&p[e]);
}

// ------- bucket histogram; also emits per-block counts for the scatter -------
__launch_bounds__(512)
__global__ void k_bhist(const int* __restrict__ eidx, int E,
                        const int* __restrict__ flag, int* __restrict__ ghist,
                        int* __restrict__ gcnt) {
    __shared__ int lh[NBUK];
    int t = threadIdx.x;
    for (int i = t; i < NBUK; i += 512) lh[i] = 0;
    __syncthreads();
    int base = blockIdx.x * CHUNK2;
    int cnt = min(CHUNK2, E - base);
    int is64 = *flag;
    const int* colp = eidx + ((size_t)E << is64);
    for (int i = t; i < cnt; i += 512)
        atomicAdd(&lh[ld_idx_nt(colp, base + i, is64) >> 7], 1);
    __syncthreads();
    for (int i = t; i < NBUK; i += 512) {
        int v = lh[i];
        gcnt[(size_t)blockIdx.x * NBUK + i] = v;     // per-block counts (coalesced)
        if (v) atomicAdd(&ghist[i], v);
    }
}

// ---------------- exact scan of 1024 bucket totals (single block) ----------------
__global__ void k_bscan(const int* __restrict__ ghist, int E, int* __restrict__ boff) {
    __shared__ int s[NBUK];
    int t = threadIdx.x;
    int v = ghist[t];
    s[t] = v;
    __syncthreads();
    for (int off = 1; off < NBUK; off <<= 1) {
        int a = (t >= off) ? s[t - off] : 0;
        __syncthreads();
        s[t] += a;
        __syncthreads();
    }
    boff[t] = s[t] - v;
    if (t == NBUK - 1) boff[NBUK] = E;
}

// ------- per-bucket scan over blocks: gcnt[b][k] -> absolute write offset -------
// one block per bucket k; exclusive scan over the nb scatter-blocks.
__launch_bounds__(512)
__global__ void k_bscan2(int* __restrict__ gcnt, const int* __restrict__ boff, int nb) {
    __shared__ int s[512];
    int t = threadIdx.x;
    int k = blockIdx.x;
    int v = (t < nb) ? gcnt[(size_t)t * NBUK + k] : 0;
    s[t] = v;
    __syncthreads();
    for (int off = 1; off < 512; off <<= 1) {
        int a = (t >= off) ? s[t - off] : 0;
        __syncthreads();
        s[t] += a;
        __syncthreads();
    }
    if (t < nb) gcnt[(size_t)t * NBUK + k] = boff[k] + (s[t] - v);
}

// ------- bucket scatter: precomputed cursors, single read pass -------
// pairs[k] = r | (c&127)<<20, grouped by bucket (c>>7)
__launch_bounds__(512)
__global__ void k_bscatter(const int* __restrict__ eidx, int E,
                           const int* __restrict__ flag,
                           const int* __restrict__ gcnt, uint32_t* __restrict__ pairs) {
    __shared__ int lcur[NBUK];
    int t = threadIdx.x;
    for (int i = t; i < NBUK; i += 512)
        lcur[i] = gcnt[(size_t)blockIdx.x * NBUK + i];
    __syncthreads();
    int base = blockIdx.x * CHUNK2;
    int cnt = min(CHUNK2, E - base);
    int is64 = *flag;
    const int* rowp = eidx;
    const int* colp = eidx + ((size_t)E << is64);
    for (int i = t; i < cnt; i += 512) {
        int e = base + i;
        int c = ld_idx_nt(colp, e, is64);
        int r = ld_idx_nt(rowp, e, is64);
        int buk = c >> 7;
        int pos = atomicAdd(&lcur[buk], 1);
        pairs[pos] = (uint32_t)r | ((uint32_t)(c & (NPB - 1)) << 20);
    }
}

// ------- per-bucket counting sort -> per-node CSR (srcs, noff) + dinv -------
__launch_bounds__(256)
__global__ void k_bsort(const uint32_t* __restrict__ pairs, const int* __restrict__ boff,
                        int* __restrict__ srcs, int* __restrict__ noff,
                        float* __restrict__ dinv, int n) {
    __shared__ int cnt[NPB];
    __shared__ int scn[NPB];
    int t = threadIdx.x;
    int b = blockIdx.x;
    if (t < NPB) cnt[t] = 0;
    __syncthreads();
    int beg = boff[b], end = boff[b + 1];
    for (int k = beg + t; k < end; k += 256)
        atomicAdd(&cnt[pairs[k] >> 20], 1);
    __syncthreads();
    if (t < NPB) scn[t] = cnt[t];
    __syncthreads();
    for (int off = 1; off < NPB; off <<= 1) {
        int v = 0;
        if (t < NPB && t >= off) v = scn[t - off];
        __syncthreads();
        if (t < NPB) scn[t] += v;
        __syncthreads();
    }
    if (t < NPB) {
        int node = b * NPB + t;
        int excl = scn[t] - cnt[t];
        if (node <= n) noff[node] = beg + excl;      // node==n lands here (last bucket)
        if (node < n)  dinv[node] = rsqrtf((float)cnt[t] + 1.0f);
        cnt[t] = beg + excl;                         // reuse as cursor
    }
    __syncthreads();
    for (int k = beg + t; k < end; k += 256) {
        uint32_t p = pairs[k];
        int pos = atomicAdd(&cnt[p >> 20], 1);
        srcs[pos] = (int)(p & 0xFFFFF);
    }
}

// ------- hs1 = (x @ W1) * dinv[row], fp16 ----------------
__launch_bounds__(256)
__global__ void k_gemm1(const float* __restrict__ x, const float* __restrict__ W1,
                        const float* __restrict__ dinv, __half* __restrict__ hs, int n) {
    __shared__ float Wt[16 * 132];
    for (int i = threadIdx.x; i < F_IN * HID; i += 256) {
        int k = i >> 4, j = i & 15;
        Wt[j * 132 + k] = W1[i];
    }
    __syncthreads();
    int row = blockIdx.x * 16 + (threadIdx.x >> 4);
    int j = threadIdx.x & 15;
    if (row >= n) return;
    const f4v* xr = (const f4v*)(x + (size_t)row * F_IN);
    float acc = 0.f;
#pragma unroll
    for (int kk = 0; kk < 32; ++kk) {
        f4v xv = __builtin_nontemporal_load(&xr[kk]);   // stream: don't pollute L2
        float4 wv = *(const float4*)&Wt[j * 132 + 4 * kk];
        acc += xv.x * wv.x + xv.y * wv.y + xv.z * wv.z + xv.w * wv.w;
    }
    hs[(size_t)row * HID + j] = __float2half(acc * dinv[row]);
}

// ------- fused GCN layer: CSR gather, register accumulate -------
// Each 16-lane group owns one node i; lane j owns feature j.
// acc = hs[i][j] + sum_{r in N(i)} hs[r][j]        (hs pre-scaled by dinv[src])
// hrelu[j] = relu(acc * dinv[i] + bias[j])
// EPI 0: out0 = fp16( (hrelu @ Wnext) * dinv )     (next layer's hs)
// EPI 1: out0 = fp16( hrelu )                      (h2 for the edge-MLP MFMA)
// NOTE: n % 16 == 0 (100000): no partial groups, uniform barriers.
template <int EPI>
__launch_bounds__(256)
__global__ void k_layer(const int* __restrict__ srcs, const int* __restrict__ noff,
                        const __half* __restrict__ hs, const float* __restrict__ dinv,
                        const float* __restrict__ bias, const float* __restrict__ Wnext,
                        __half* __restrict__ out0) {
    __shared__ float Ws[256];
    __shared__ float bs[16];
    __shared__ float srow[16 * 17];
    int t = threadIdx.x;
    if (EPI == 0) { if (t < 256) Ws[t] = Wnext[t]; }
    if (t < 16) bs[t] = bias[t];
    __syncthreads();

    int i = blockIdx.x * 16 + (t >> 4);    // node
    int j = t & 15;                        // feature
    int beg = noff[i], end = noff[i + 1];
    float acc = __half2float(hs[(size_t)i * HID + j]);   // self-loop term

    int kb = beg;
    for (; kb + 16 <= end; kb += 16) {
        int idx = __builtin_nontemporal_load(&srcs[kb + j]);   // coalesced stream
#pragma unroll
        for (int m = 0; m < 16; ++m) {
            int r = __shfl(idx, m, 16);    // broadcast within the 16-lane group
            acc += __half2float(hs[(size_t)r * HID + j]);
        }
    }
    if (kb < end) {
        int lim = end - kb;
        int idx = srcs[kb + ((j < lim) ? j : (lim - 1))];
        for (int m = 0; m < lim; ++m) {
            int r = __shfl(idx, m, 16);
            acc += __half2float(hs[(size_t)r * HID + j]);
        }
    }

    float di = dinv[i];
    float hrelu = fmaxf(acc * di + bs[j], 0.f);
    if (EPI == 1) {
        out0[(size_t)i * HID + j] = __float2half(hrelu);
        return;
    }
    int ln = t >> 4;
    srow[ln * 17 + j] = hrelu;
    __syncthreads();
    float a0 = 0.f;
#pragma unroll
    for (int k = 0; k < 16; ++k) a0 += srow[ln * 17 + k] * Ws[k * 16 + j];
    out0[(size_t)i * HID + j] = __float2half(a0 * di);
}

// ------- edge MLP via MFMA (swapped operands): D[z][edge] -------
// A = fc1W^T [16 z x 32 k] (persistent), B = [h2[r]|h2[c]] [32 k x 16 edges].
// C/D layout: col = lane&15 = EDGE, row = (lane>>4)*4+q = z  [m89 verified]
// => each lane holds 4 z-values of ONE edge; logit reduce = 4 FMA + 2 shfl_xor.
#define EDGE_ITER 8
__launch_bounds__(256)
__global__ void k_edge(const int* __restrict__ eidx, int E,
                       const int* __restrict__ flag,
                       const _Float16* __restrict__ h2,
                       const float* __restrict__ fc1W, const float* __restrict__ fc1b,
                       const float* __restrict__ fc2W, const float* __restrict__ fc2b,
                       float* __restrict__ out) {
    int t = threadIdx.x;
    int l = t & 63;
    int wv = t >> 6;                       // wave 0..3
    int m = l & 15;                        // edge slot (B col / D col)
    int g = l >> 4;                        // 0..3
    int side = g >> 1;                     // 0 -> r, 1 -> c
    int part = g & 1;                      // which 8-feature half

    // persistent A fragment: A[z=m][k=8g+j] = fc1W[(8g+j)*16 + m]
    h8 af;
#pragma unroll
    for (int j = 0; j < 8; ++j)
        af[j] = (_Float16)fc1W[(8 * g + j) * 16 + m];
    // C init: b1 per z-row; z = 4g+q
    f4v cinit;
#pragma unroll
    for (int q = 0; q < 4; ++q) cinit[q] = fc1b[4 * g + q];
    // fc2 weights for this lane's 4 z-rows
    float w2x[4], w2y[4];
#pragma unroll
    for (int q = 0; q < 4; ++q) {
        w2x[q] = fc2W[(4 * g + q) * 2];
        w2y[q] = fc2W[(4 * g + q) * 2 + 1];
    }
    float b20 = fc2b[0], b21 = fc2b[1];

    int is64 = *flag;
    const int* rowp = eidx;
    const int* colp = eidx + ((size_t)E << is64);
    const int* idxp = side ? colp : rowp;

    for (int it = 0; it < EDGE_ITER; ++it) {
        int grp = (blockIdx.x * EDGE_ITER + it) * 4 + wv;
        int base = grp * 16;
        if (base >= E) return;
        int eA = base + m;
        if (eA >= E) eA = E - 1;
        int node = ld_idx_nt(idxp, eA, is64);
        h8 bv = *(const h8*)(h2 + (size_t)node * HID + part * 8);
        f4v z = __builtin_amdgcn_mfma_f32_16x16x32_f16(af, bv, cinit, 0, 0, 0);
        // partial logits over this lane's 4 z-rows
        float v0 = 0.f, v1 = 0.f;
#pragma unroll
        for (int q = 0; q < 4; ++q) {
            float zr = fmaxf(z[q], 0.f);
            v0 += zr * w2x[q];
            v1 += zr * w2y[q];
        }
        // reduce across the 4 lane-groups (same edge in lanes m, m+16, m+32, m+48)
        v0 += __shfl_xor(v0, 16); v0 += __shfl_xor(v0, 32);
        v1 += __shfl_xor(v1, 16); v1 += __shfl_xor(v1, 32);
        float a = b20 + v0, b = b21 + v1;
        float mm = fmaxf(a, b);
        float lse = mm + __logf(__expf(a - mm) + __expf(b - mm));
        if (g == 0 && base + m < E) {
            f2v res; res.x = a - lse; res.y = b - lse;
            __builtin_nontemporal_store(res, (f2v*)(out + 2 * (size_t)(base + m)));
        }
    }
}

static inline size_t rnd4(size_t v) { return (v + 3) & ~(size_t)3; }

extern "C" void kernel_launch(void* const* d_in, const int* in_sizes, int n_in,
                              void* d_out, int out_size, void* d_ws, size_t ws_size,
                              hipStream_t stream) {
    const float* x    = (const float*)d_in[0];
    const int*   eidx = (const int*)d_in[1];
    const float* W1   = (const float*)d_in[2];
    const float* b1   = (const float*)d_in[3];
    const float* W2   = (const float*)d_in[4];
    const float* b2   = (const float*)d_in[5];
    const float* fc1W = (const float*)d_in[6];
    const float* fc1b = (const float*)d_in[7];
    const float* fc2W = (const float*)d_in[8];
    const float* fc2b = (const float*)d_in[9];

    const int n = in_sizes[0] / F_IN;   // 100000 (divisible by 16)
    const int E = in_sizes[1] / 2;      // 3200000
    const int NBLK_SCAT = (E + CHUNK2 - 1) / CHUNK2;   // 196 (<=512 for k_bscan2)
    const int NBLK_BUK  = (n + NPB - 1) / NPB;         // 782

    // workspace carve-up (float units, 16B-aligned regions)
    float* ws = (float*)d_ws;
    size_t a = 0;
    float*    dinv  = ws + a;              a += rnd4(n);
    uint32_t* pairs = (uint32_t*)(ws + a); a += rnd4(E);
    int*      srcs  = (int*)(ws + a);      a += rnd4(E);
    int*      noff  = (int*)(ws + a);      a += rnd4(n + 1);
    int*      boff  = (int*)(ws + a);      a += rnd4(NBUK + 1);
    int*      ghist = (int*)(ws + a);      a += NBUK;
    int*      flag  = (int*)(ws + a);      a += 4;
    int*      gcnt  = (int*)(ws + a);      a += rnd4((size_t)NBLK_SCAT * NBUK);
    __half*   hs1   = (__half*)(ws + a);   a += rnd4((size_t)n * HID / 2);
    __half*   hs2   = (__half*)(ws + a);   a += rnd4((size_t)n * HID / 2);
    __half*   h2b   = (__half*)(ws + a);   a += rnd4((size_t)n * HID / 2);
    float* out = (float*)d_out;

    k_detect<<<1, 64, 0, stream>>>(eidx, flag);

    // ---- two-level bucket sort -> per-node CSR (shared by both layers) ----
    (void)hipMemsetAsync(ghist, 0, NBUK * sizeof(int), stream);
    k_bhist<<<NBLK_SCAT, 512, 0, stream>>>(eidx, E, flag, ghist, gcnt);
    k_bscan<<<1, NBUK, 0, stream>>>(ghist, E, boff);
    k_bscan2<<<NBUK, 512, 0, stream>>>(gcnt, boff, NBLK_SCAT);
    k_bscatter<<<NBLK_SCAT, 512, 0, stream>>>(eidx, E, flag, gcnt, pairs);
    k_bsort<<<NBLK_BUK, 256, 0, stream>>>(pairs, boff, srcs, noff, dinv, n);

    // ---- dense prologue: hs1 = (x@W1)*dinv (fp16) ----
    k_gemm1<<<(n + 15) / 16, 256, 0, stream>>>(x, W1, dinv, hs1, n);

    // ---- layer 1 (epilogue: hs2 = relu(gcn)@W2 * dinv, fp16) ----
    k_layer<0><<<n / 16, 256, 0, stream>>>(srcs, noff, hs1, dinv, b1, W2, hs2);
    // ---- layer 2 (plain relu output h2, fp16: 3.2 MB, fits per-XCD L2) ----
    k_layer<1><<<n / 16, 256, 0, stream>>>(srcs, noff, hs2, dinv, b2, nullptr, h2b);
    // ---- edge MLP + log_softmax via MFMA (16 edges per mfma) ----
    {
        int ngrp = (E + 15) / 16;                                  // 200000
        int nblk = (ngrp + 4 * EDGE_ITER - 1) / (4 * EDGE_ITER);   // 6250
        k_edge<<<nblk, 256, 0, stream>>>(eidx, E, flag, (const _Float16*)h2b,
                                         fc1W, fc1b, fc2W, fc2b, out);
    }
}